// Round 3
// baseline (162.507 us; speedup 1.0000x reference)
//
#include <hip/hip_runtime.h>
#include <math.h>

#define BATCH_N 16384

typedef _Float16 half8 __attribute__((ext_vector_type(8)));
typedef __fp16 h2 __attribute__((ext_vector_type(2)));   // cvt_pkrtz / fdot2 type
typedef float f32x4 __attribute__((ext_vector_type(4)));

// ---------------------------------------------------------------------------
// Monolith, 16 samples/block (grid 1024), 256 threads, 4 blocks/CU.
// LDS float-index map (10020 floats = 40080 B -> 4 blocks/CU):
//  [0,120)      C1P   conv1 w as f16 pairs [oc][ky][4]
//  [120,128)    BS1   conv1 bias (6 used)
//  [128,144)    BS2   conv2 bias
//  [144,240)    ROTM  12 gates x 8 (batch-uniform Rot matrices)
//  [240,368)    RXCS  rx cos[64] + sin[64]  (16 samples x 4 qubits)
//  [368,420)    CWB   clf w (40) + b (10)
//  [420,2276)   W2B   conv2 w f16 [16 oc][232]
//  [2276,10020) PW    per-wave scratch, 1936 floats (3872 halves) each:
//     halves [0,1568)    XH  x-pair f16 [2 s][28 rows][28 cols]
//     halves [1568,3872) H1C f16 [2 s][144 units][8]  (unit = py*12+px)
//   fc1-phase overlay of PW (XH/H1C dead):
//     halves [0,4224)    H2A f16 [16 s][264]  (264-stride kills fc1 bank conflicts)
//     halves [4224,6400) HS  f16 [16 s][136]  (fc1 out, 136-stride for fc2 reads)
// ---------------------------------------------------------------------------
#define C1P_F  0
#define BS1_F  120
#define BS2_F  128
#define ROTM_F 144
#define RXCS_F 240
#define CWB_F  368
#define W2B_F  420
#define PW_F   2276
#define LDS_FLOATS 10020

#define WV_STRIDE_H 3872   // per-wave halves
#define XH_SAMP_H   784    // 28x28 halves per sample
#define H1_OFF_H    1568   // H1C offset within wave scratch (halves)
#define H1_SAMP_H   1152   // 144 units x 8
#define H2A_ROW_H   264    // H2A row stride (halves)
#define HS_OFF_H    4224   // HS offset within PW (halves)
#define HS_ROW_H    136    // HS row stride (halves)

static __device__ __forceinline__ h2 u2h(unsigned u) {
    union { unsigned u; h2 h; } c; c.u = u; return c.h;
}

struct Row5 { h2 a0, a1, a2, s0, s1; };
static __device__ __forceinline__ Row5 ldrow(const unsigned* xw) {
    const unsigned u0 = xw[0], u1 = xw[1], u2 = xw[2];
    Row5 r;
    r.a0 = u2h(u0); r.a1 = u2h(u1); r.a2 = u2h(u2);
    r.s0 = u2h((u0 >> 16) | (u1 << 16));
    r.s1 = u2h((u1 >> 16) | (u2 << 16));
    return r;
}

__global__ __launch_bounds__(256, 4) void fused_model(
    const float* __restrict__ xg,
    const float* __restrict__ c1w, const float* __restrict__ c1b,
    const float* __restrict__ c2w, const float* __restrict__ c2b,
    const float* __restrict__ f1w, const float* __restrict__ f1b,
    const float* __restrict__ f2w, const float* __restrict__ f2b,
    const float* __restrict__ qw,  const float* __restrict__ cw,
    const float* __restrict__ cbias, float* __restrict__ out) {
    __shared__ float L[LDS_FLOATS];
    const int tid = threadIdx.x;
    const int b0 = blockIdx.x * 16;
    const int lane = tid & 63, wvi = tid >> 6;
    const int ml = lane & 15, q = lane >> 4;

    _Float16* W2BH = (_Float16*)(L + W2B_F);
    _Float16* PWH  = (_Float16*)(L + PW_F);
    _Float16* XHH  = PWH + wvi * WV_STRIDE_H;
    _Float16* H1CH = XHH + H1_OFF_H;
    _Float16* H2AH = PWH;             // overlay (valid after conv phase)
    _Float16* HSH  = PWH + HS_OFF_H;  // overlay

    // ================= stage shared constants (one barrier) ================
    if (tid < 120) {  // conv1 weight f16 pairs
        const int oc = tid / 20, r = tid - oc * 20, ky = r >> 2, j = r & 3;
        const float* wb = c1w + oc * 25 + ky * 5;
        float lo, hi;
        if (j == 0)      { lo = wb[0]; hi = wb[1]; }
        else if (j == 1) { lo = wb[2]; hi = wb[3]; }
        else if (j == 2) { lo = wb[4]; hi = 0.f;   }
        else             { lo = 0.f;   hi = wb[4]; }
        ((h2*)&L[C1P_F])[tid] = __builtin_amdgcn_cvt_pkrtz(lo, hi);
    }
    if (tid < 6)  L[BS1_F + tid] = c1b[tid];
    if (tid < 16) L[BS2_F + tid] = c2b[tid];
    if (tid < 40) L[CWB_F + tid] = cw[tid];
    if (tid < 10) L[CWB_F + 40 + tid] = cbias[tid];
    if (tid < 12) {  // Rot gate matrices (batch-uniform)
        const float phi = qw[tid * 3 + 0];
        const float th  = qw[tid * 3 + 1];
        const float om  = qw[tid * 3 + 2];
        const float ct = cosf(0.5f * th), st = sinf(0.5f * th);
        const float ap = 0.5f * (phi + om), bm = 0.5f * (phi - om);
        const float ca = cosf(ap), sa = sinf(ap);
        const float cbm = cosf(bm), sbm = sinf(bm);
        float* R = &L[ROTM_F + tid * 8];
        R[0] =  ct * ca;  R[1] = -ct * sa;
        R[2] = -st * cbm; R[3] = -st * sbm;
        R[4] =  st * cbm; R[5] = -st * sbm;
        R[6] =  ct * ca;  R[7] =  ct * sa;
    }
    {   // conv2 weights, incremental oc/r (no div in loop)
        int oc = (tid >= 232) ? 1 : 0;
        int r = tid - oc * 232;
#pragma unroll 1
        for (int i = tid; i < 3712; i += 256) {
            float v = 0.f;
            if (r < 200) {
                const int pix = r >> 3, ic = r & 7;
                if (ic < 6) v = c2w[oc * 150 + ic * 25 + pix];
            }
            W2BH[oc * 232 + r] = (_Float16)v;
            r += 24; oc += 1;
            if (r >= 232) { r -= 232; oc += 1; }
        }
    }
    __syncthreads();

    // ========== per-wave conv1+conv2 for two sample pairs ==================
    unsigned h2r[2][2][4];   // [p][si][t] conv2 pooled f16x2 (lanes<32 valid)

#pragma unroll 2
    for (int p = 0; p < 2; ++p) {
        const int sbase = b0 + 4 * wvi + 2 * p;

        // ---- stage x pair -> XH f16 (coalesced float4 burst) ------------
        for (int k = lane; k < 392; k += 64) {
            const int s = (k >= 196) ? 1 : 0;
            const int kk = k - 196 * s;
            const int row = kk / 7, q4 = kk - row * 7;
            const float4 v = *(const float4*)(xg + (size_t)(sbase + s) * 784 + row * 28 + q4 * 4);
            union { h2 h[2]; uint2 u; } W;
            W.h[0] = __builtin_amdgcn_cvt_pkrtz(v.x, v.y);
            W.h[1] = __builtin_amdgcn_cvt_pkrtz(v.z, v.w);
            *(uint2*)(XHH + s * XH_SAMP_H + row * 28 + q4 * 4) = W.u;
        }
        __builtin_amdgcn_wave_barrier();

        // ---- conv1 (dot2 f16 from LDS) -> H1C ---------------------------
        for (int t = lane; t < 288; t += 64) {
            const int s = t >= 144 ? 1 : 0;
            const int r = t - s * 144;
            const int py = r / 12, px = r - (r / 12) * 12;
            const unsigned* xw = (const unsigned*)(XHH + s * XH_SAMP_H) + 2 * py * 14 + px;

            float acc[6][4];
#pragma unroll
            for (int oc = 0; oc < 6; oc++) {
                const float bv = L[BS1_F + oc];
                acc[oc][0] = bv; acc[oc][1] = bv; acc[oc][2] = bv; acc[oc][3] = bv;
            }

            Row5 R0 = ldrow(xw);
#pragma unroll
            for (int ky = 0; ky < 5; ky++) {
                const Row5 R1 = ldrow(xw + (ky + 1) * 14);
#pragma unroll
                for (int oc = 0; oc < 6; oc++) {
                    union { uint4 v; h2 h[4]; } W;
                    W.v = ((const uint4*)&L[C1P_F])[oc * 5 + ky];
                    acc[oc][0] = __builtin_amdgcn_fdot2(R0.a0, W.h[0], acc[oc][0], false);
                    acc[oc][0] = __builtin_amdgcn_fdot2(R0.a1, W.h[1], acc[oc][0], false);
                    acc[oc][0] = __builtin_amdgcn_fdot2(R0.a2, W.h[2], acc[oc][0], false);
                    acc[oc][1] = __builtin_amdgcn_fdot2(R0.s0, W.h[0], acc[oc][1], false);
                    acc[oc][1] = __builtin_amdgcn_fdot2(R0.s1, W.h[1], acc[oc][1], false);
                    acc[oc][1] = __builtin_amdgcn_fdot2(R0.a2, W.h[3], acc[oc][1], false);
                    acc[oc][2] = __builtin_amdgcn_fdot2(R1.a0, W.h[0], acc[oc][2], false);
                    acc[oc][2] = __builtin_amdgcn_fdot2(R1.a1, W.h[1], acc[oc][2], false);
                    acc[oc][2] = __builtin_amdgcn_fdot2(R1.a2, W.h[2], acc[oc][2], false);
                    acc[oc][3] = __builtin_amdgcn_fdot2(R1.s0, W.h[0], acc[oc][3], false);
                    acc[oc][3] = __builtin_amdgcn_fdot2(R1.s1, W.h[1], acc[oc][3], false);
                    acc[oc][3] = __builtin_amdgcn_fdot2(R1.a2, W.h[3], acc[oc][3], false);
                }
                R0 = R1;
            }

            union { _Float16 h[8]; uint4 u; } O;
#pragma unroll
            for (int oc = 0; oc < 6; oc++) {
                const float m = fmaxf(fmaxf(acc[oc][0], acc[oc][1]), fmaxf(acc[oc][2], acc[oc][3]));
                O.h[oc] = (_Float16)fmaxf(m, 0.f);
            }
            O.h[6] = (_Float16)0.f; O.h[7] = (_Float16)0.f;
            *(uint4*)(H1CH + s * H1_SAMP_H + (py * 12 + px) * 8) = O.u;
        }
        __builtin_amdgcn_wave_barrier();

        // ---- conv2 via MFMA (b128 fragments) -> h2r regs ----------------
        {
            f32x4 c2a[2][4];
#pragma unroll
            for (int a = 0; a < 2; a++)
#pragma unroll
                for (int b = 0; b < 4; b++) c2a[a][b] = (f32x4){0.f, 0.f, 0.f, 0.f};

#pragma unroll
            for (int ks = 0; ks < 7; ks++) {
                const half8 bfrag = *(const half8*)(W2BH + ml * 232 + ks * 32 + q * 8);
                int tp = ks * 4 + q; if (tp > 24) tp = 24;  // pad taps: B=0
                const int poff = (tp / 5) * 12 + (tp % 5);
#pragma unroll
                for (int si = 0; si < 2; si++) {
                    const _Float16* hp = H1CH + si * H1_SAMP_H;
#pragma unroll
                    for (int t = 0; t < 4; t++) {
                        const int cp = t * 16 + ml;
                        const int unit = (cp >> 3) * 12 + (cp & 7) + poff;
                        const half8 afrag = *(const half8*)(hp + unit * 8);
                        c2a[si][t] = __builtin_amdgcn_mfma_f32_16x16x32_f16(afrag, bfrag, c2a[si][t], 0, 0, 0);
                    }
                }
            }

            // bias + pool + relu -> registers (dumped to LDS after conv phase)
            const float bv = L[BS2_F + ml];
#pragma unroll
            for (int si = 0; si < 2; si++) {
#pragma unroll
                for (int t = 0; t < 4; t++) {
                    const float c0 = c2a[si][t][0] + bv, c1 = c2a[si][t][1] + bv;
                    const float c2 = c2a[si][t][2] + bv, c3 = c2a[si][t][3] + bv;
                    float px0 = fmaxf(c0, c1), px1 = fmaxf(c2, c3);
                    px0 = fmaxf(px0, __shfl_xor(px0, 32));
                    px1 = fmaxf(px1, __shfl_xor(px1, 32));
                    union { _Float16 h[2]; unsigned u; } P2;
                    P2.h[0] = (_Float16)fmaxf(px0, 0.f);
                    P2.h[1] = (_Float16)fmaxf(px1, 0.f);
                    h2r[p][si][t] = P2.u;
                }
            }
        }
        __builtin_amdgcn_wave_barrier();
    }
    __syncthreads();

    // ============ dump H2 regs -> H2A overlay (XH/H1C dead) ================
    if (lane < 32) {
#pragma unroll
        for (int p = 0; p < 2; p++)
#pragma unroll
            for (int si = 0; si < 2; si++)
#pragma unroll
                for (int t = 0; t < 4; t++) {
                    const int srow = 4 * wvi + 2 * p + si;
                    *(unsigned*)(H2AH + srow * H2A_ROW_H + ml * 16 + t * 4 + q * 2) = h2r[p][si][t];
                }
    }
    __syncthreads();

    // ============ fc1 (256->120) via MFMA, M=16 samples ====================
    {
        f32x4 fcC[2];
        fcC[0] = (f32x4){0.f, 0.f, 0.f, 0.f};
        fcC[1] = (f32x4){0.f, 0.f, 0.f, 0.f};
        const _Float16* h2p = H2AH + ml * H2A_ROW_H;  // sample = ml
#pragma unroll
        for (int ks = 0; ks < 8; ks++) {
            const half8 afrag = *(const half8*)(h2p + ks * 32 + q * 8);
#pragma unroll
            for (int ti = 0; ti < 2; ti++) {
                const int n = (wvi + 4 * ti) * 16 + ml;
                half8 bfrag;
                if (n < 120) {
                    const float* wp = f1w + (size_t)n * 256 + ks * 32 + q * 8;
                    const float4 u = *(const float4*)wp;
                    const float4 v = *(const float4*)(wp + 4);
                    union { h2 p[4]; half8 h8; } B;
                    B.p[0] = __builtin_amdgcn_cvt_pkrtz(u.x, u.y);
                    B.p[1] = __builtin_amdgcn_cvt_pkrtz(u.z, u.w);
                    B.p[2] = __builtin_amdgcn_cvt_pkrtz(v.x, v.y);
                    B.p[3] = __builtin_amdgcn_cvt_pkrtz(v.z, v.w);
                    bfrag = B.h8;
                } else {
#pragma unroll
                    for (int j = 0; j < 8; j++) bfrag[j] = (_Float16)0.f;
                }
                fcC[ti] = __builtin_amdgcn_mfma_f32_16x16x32_f16(afrag, bfrag, fcC[ti], 0, 0, 0);
            }
        }
        // C: col=ml -> neuron, row=q*4+rg -> sample (all 16 valid)
#pragma unroll
        for (int ti = 0; ti < 2; ti++) {
            const int n = (wvi + 4 * ti) * 16 + ml;
            if (n < 120) {
                const float bb = f1b[n];
#pragma unroll
                for (int rg = 0; rg < 4; rg++) {
                    const int s = q * 4 + rg;
                    HSH[s * HS_ROW_H + n] = (_Float16)fmaxf(fcC[ti][rg] + bb, 0.f);
                }
            }
        }
    }
    __syncthreads();

    // ====== fc2 (120->4) + pi*sigmoid, 256 threads (4-way split-K) =========
    {
        const int s = tid >> 4, m = (tid >> 2) & 3, part = tid & 3;
        float f = (part == 0) ? f2b[m] : 0.f;
#pragma unroll
        for (int i = 0; i < 4; ++i) {
            const int bblk = part + 4 * i;
            if (bblk < 15) {
                const half8 hv = *(const half8*)(HSH + s * HS_ROW_H + bblk * 8);
                const float* wp = f2w + m * 120 + bblk * 8;
                const float4 w0 = *(const float4*)wp;
                const float4 w1 = *(const float4*)(wp + 4);
                f = fmaf(w0.x, (float)hv[0], f); f = fmaf(w0.y, (float)hv[1], f);
                f = fmaf(w0.z, (float)hv[2], f); f = fmaf(w0.w, (float)hv[3], f);
                f = fmaf(w1.x, (float)hv[4], f); f = fmaf(w1.y, (float)hv[5], f);
                f = fmaf(w1.z, (float)hv[6], f); f = fmaf(w1.w, (float)hv[7], f);
            }
        }
        f += __shfl_xor(f, 1);
        f += __shfl_xor(f, 2);
        if (part == 0) {
            const float ang = 3.14159265358979323846f / (1.f + expf(-f));
            L[RXCS_F + s * 4 + m]      = cosf(0.5f * ang);
            L[RXCS_F + 64 + s * 4 + m] = sinf(0.5f * ang);
        }
    }
    __syncthreads();

    // ============ circuit: 16 samples x 16 amplitudes on 4 waves ===========
    {
        const int s = tid >> 4, a = tid & 15;
        float ar = (a == 0) ? 1.f : 0.f, ai = 0.f;

#pragma unroll
        for (int l = 0; l < 3; l++) {
#pragma unroll
            for (int w = 0; w < 4; w++) {
                const float* R = &L[ROTM_F + (l * 4 + w) * 8];
                const int mask = 8 >> w;
                const float pr = __shfl_xor(ar, mask);
                const float pi = __shfl_xor(ai, mask);
                const bool bit = (a & mask) != 0;
                const float lr = bit ? pr : ar, li = bit ? pi : ai;
                const float hr = bit ? ar : pr, hi = bit ? ai : pi;
                const float Ar = bit ? R[4] : R[0], Ai = bit ? R[5] : R[1];
                const float Br = bit ? R[6] : R[2], Bi = bit ? R[7] : R[3];
                ar = Ar * lr - Ai * li + Br * hr - Bi * hi;
                ai = Ar * li + Ai * lr + Br * hi + Bi * hr;
            }
#pragma unroll
            for (int w = 0; w < 4; w++) {
                const int mc = 8 >> w, mt = 8 >> ((w + 1) & 3);
                const float pr = __shfl_xor(ar, mt);
                const float pi = __shfl_xor(ai, mt);
                const bool ctrl = (a & mc) != 0;
                ar = ctrl ? pr : ar;
                ai = ctrl ? pi : ai;
            }
#pragma unroll
            for (int w = 0; w < 4; w++) {
                const int mask = 8 >> w;
                const float c  = L[RXCS_F + s * 4 + w];
                const float s2 = L[RXCS_F + 64 + s * 4 + w];
                const float pr = __shfl_xor(ar, mask);
                const float pi = __shfl_xor(ai, mask);
                const float nr = fmaf(c, ar, s2 * pi);
                const float ni = fmaf(c, ai, -s2 * pr);
                ar = nr; ai = ni;
            }
        }

        float v = ar * ar + ai * ai;
#pragma unroll
        for (int d = 1; d < 16; d <<= 1) {
            const float pv = __shfl_xor(v, d);
            v = (a & d) ? (pv - v) : (v + pv);
        }

        if (a < 10) {
            const int base = (tid & 63) & ~15;
            float lg = L[CWB_F + 40 + a];
#pragma unroll
            for (int w = 0; w < 4; w++) {
                const float zw = __shfl(v, base | (8 >> w));
                lg = fmaf(L[CWB_F + a * 4 + w], zw, lg);
            }
            out[(size_t)(b0 + s) * 10 + a] = lg;
        }
    }
}

// ---------------------------------------------------------------------------
extern "C" void kernel_launch(void* const* d_in, const int* in_sizes, int n_in,
                              void* d_out, int out_size, void* d_ws, size_t ws_size,
                              hipStream_t stream) {
    const float* x   = (const float*)d_in[0];
    const float* c1w = (const float*)d_in[1];
    const float* c1b = (const float*)d_in[2];
    const float* c2w = (const float*)d_in[3];
    const float* c2b = (const float*)d_in[4];
    const float* f1w = (const float*)d_in[5];
    const float* f1b = (const float*)d_in[6];
    const float* f2w = (const float*)d_in[7];
    const float* f2b = (const float*)d_in[8];
    const float* qw  = (const float*)d_in[9];
    const float* cw  = (const float*)d_in[10];
    const float* cb  = (const float*)d_in[11];
    float* out = (float*)d_out;

    fused_model<<<BATCH_N / 16, 256, 0, stream>>>(x, c1w, c1b, c2w, c2b,
                                                  f1w, f1b, f2w, f2b,
                                                  qw, cw, cb, out);
}